// Round 13
// baseline (418.652 us; speedup 1.0000x reference)
//
#include <hip/hip_runtime.h>
#include <hip/hip_bf16.h>
#include <cmath>

#define N_TOTAL 4096
#define HALF_N  2048
#define D_DIM   512

// ws layout (bytes):
//   [0,      16384) float sq[4096]
//   [16384,  20480) float colsum[1024]   [zeroed]
//   [20480,  20496) double sumsq[2]      [zeroed]
//   [20520,  20532) float bw[3]          (written by k_bw)
//   [24576,  24576+2080*24) double partials[2080][3]  (pxy, pdg_src, pdg_tgt; written unconditionally)

#define P_OFF 24576

// ---------------- Kernel 1: row norms, column sums, sum-of-norms ----------------
__global__ __launch_bounds__(256) void k_rowstats(const float* __restrict__ x,
                                                  float* __restrict__ sq,
                                                  float* __restrict__ colsum,
                                                  double* __restrict__ sumsq) {
    __shared__ float cs[512];
    const int tid = threadIdx.x;
    cs[tid] = 0.f; cs[tid + 256] = 0.f;
    __syncthreads();

    const int w = tid >> 6, l = tid & 63;
    const int rb = blockIdx.x * 16;

    float colacc[8] = {0.f,0.f,0.f,0.f,0.f,0.f,0.f,0.f};
    double mysq = 0.0;

    #pragma unroll
    for (int r4 = 0; r4 < 4; ++r4) {
        const int row = rb + w + 4 * r4;
        const float4* p = (const float4*)(x + (size_t)row * D_DIM);
        float4 v0 = p[2 * l];
        float4 v1 = p[2 * l + 1];
        colacc[0] += v0.x; colacc[1] += v0.y; colacc[2] += v0.z; colacc[3] += v0.w;
        colacc[4] += v1.x; colacc[5] += v1.y; colacc[6] += v1.z; colacc[7] += v1.w;
        float s = v0.x*v0.x + v0.y*v0.y + v0.z*v0.z + v0.w*v0.w
                + v1.x*v1.x + v1.y*v1.y + v1.z*v1.z + v1.w*v1.w;
        #pragma unroll
        for (int off = 32; off; off >>= 1) s += __shfl_xor(s, off);
        if (l == 0) { sq[row] = s; mysq += (double)s; }
    }

    const int half = (rb < HALF_N) ? 0 : 1;
    if (l == 0) atomicAdd(&sumsq[half], mysq);

    #pragma unroll
    for (int k2 = 0; k2 < 8; ++k2) atomicAdd(&cs[8 * l + k2], colacc[k2]);
    __syncthreads();

    float* dst = colsum + half * 512;
    atomicAdd(&dst[tid],       cs[tid]);
    atomicAdd(&dst[tid + 256], cs[tid + 256]);
}

// ---------------- Kernel 2: bandwidths from analytic sums ----------------
__global__ __launch_bounds__(256) void k_bw(const float* __restrict__ colsum,
                                            const double* __restrict__ sumsq,
                                            float* __restrict__ bw) {
    const int tid = threadIdx.x;
    double pss = 0, ptt = 0, pst = 0;
    for (int c = tid; c < 512; c += 256) {
        double a = colsum[c], b = colsum[512 + c];
        pss += a * a; ptt += b * b; pst += a * b;
    }
    #pragma unroll
    for (int off = 32; off; off >>= 1) {
        pss += __shfl_xor(pss, off);
        ptt += __shfl_xor(ptt, off);
        pst += __shfl_xor(pst, off);
    }
    __shared__ double red[4][3];
    const int w = tid >> 6, l = tid & 63;
    if (l == 0) { red[w][0] = pss; red[w][1] = ptt; red[w][2] = pst; }
    __syncthreads();
    if (tid == 0) {
        double ss = red[0][0] + red[1][0] + red[2][0] + red[3][0];
        double tt = red[0][1] + red[1][1] + red[2][1] + red[3][1];
        double st = red[0][2] + red[1][2] + red[2][2] + red[3][2];
        const double n = (double)HALF_N;
        double Sss = 2.0 * n * sumsq[0] - 2.0 * ss;
        double Stt = 2.0 * n * sumsq[1] - 2.0 * tt;
        double Sst = n * (sumsq[0] + sumsq[1]) - 2.0 * st;
        const double denom = (double)N_TOTAL * (double)N_TOTAL - (double)N_TOTAL;
        bw[0] = (float)(Sss / denom);
        bw[1] = (float)(Stt / denom);
        bw[2] = (float)((Sss + Stt + 2.0 * Sst) / denom * 0.25);
    }
}

// ---------------- Kernel 3: single-wave barrier-free tiles ----------------
// 64 threads = 1 wave per block; BM=64 tile; T=8x8 micro-tile (FMA:read ratio 16,
// the fp32 LDS-economy optimum). No __syncthreads anywhere: same-wave LDS ordering
// is program order. 2080 flat-tri blocks -> 8.1/CU balance; LDS 18.4KB -> 8 blocks/CU.
#define BM 64
#define BK 32
#define LDP 36     // row stride in dwords (144 B): staging writes at 32B/bank floor, reads conflict-free (R9/R12: 0)
#define NTILE 64
#define NWORK 2080

__global__ __launch_bounds__(64, 2) void k_main(const float* __restrict__ x,
                                                const float* __restrict__ sq,
                                                const float* __restrict__ bw,
                                                double* __restrict__ partials) {
    const int t = blockIdx.x;
    int bi = (int)((129.0f - sqrtf((float)(16641 - 8 * t))) * 0.5f);
    if (bi < 0) bi = 0;
    if (bi > NTILE - 1) bi = NTILE - 1;
    while (bi > 0 && (64 * bi - bi * (bi - 1) / 2) > t) --bi;
    while (bi < NTILE - 1 && (64 * (bi + 1) - (bi + 1) * bi / 2) <= t) ++bi;
    const int bj = bi + (t - (64 * bi - bi * (bi - 1) / 2));

    __shared__ float As[BM * LDP];
    __shared__ float Bs[BM * LDP];

    const int tid = threadIdx.x;          // 0..63, one wave
    const int tx = tid & 7, ty = tid >> 3; // 8x8 thread grid
    const int i0 = bi * BM, j0 = bj * BM;

    float c[8][8];
    #pragma unroll
    for (int i = 0; i < 8; ++i)
        #pragma unroll
        for (int j = 0; j < 8; ++j) c[i][j] = 0.f;

    // full-tile register prefetch: 8 float4 A + 8 float4 B per thread
    float4 rA[8], rB[8];
    #pragma unroll
    for (int u = 0; u < 8; ++u) {
        const int f = tid + 64 * u;       // 0..511
        const int row = f >> 3, q = f & 7;
        rA[u] = *(const float4*)(x + (size_t)(i0 + row) * D_DIM + 4 * q);
        rB[u] = *(const float4*)(x + (size_t)(j0 + row) * D_DIM + 4 * q);
    }

    for (int t0 = 0; t0 < D_DIM / BK; ++t0) {
        // stage current tile regs -> LDS (b128 writes, bank-floor distribution)
        #pragma unroll
        for (int u = 0; u < 8; ++u) {
            const int f = tid + 64 * u;
            const int row = f >> 3, q = f & 7;
            *(float4*)&As[row * LDP + 4 * q] = rA[u];
            *(float4*)&Bs[row * LDP + 4 * q] = rB[u];
        }
        // issue next tile's global loads; land under the FMA loop
        if (t0 + 1 < D_DIM / BK) {
            const int k0n = (t0 + 1) * BK;
            #pragma unroll
            for (int u = 0; u < 8; ++u) {
                const int f = tid + 64 * u;
                const int row = f >> 3, q = f & 7;
                rA[u] = *(const float4*)(x + (size_t)(i0 + row) * D_DIM + k0n + 4 * q);
                rB[u] = *(const float4*)(x + (size_t)(j0 + row) * D_DIM + k0n + 4 * q);
            }
        }

        // compute: 8 k-quads; per qd: 16 b128 reads feed 256 FMAs (ratio 16)
        #pragma unroll
        for (int qd = 0; qd < 8; ++qd) {
            float4 a4[8], b4[8];
            #pragma unroll
            for (int i = 0; i < 8; ++i)
                a4[i] = *(const float4*)&As[(8 * i + ty) * LDP + 4 * qd];
            #pragma unroll
            for (int j = 0; j < 8; ++j)
                b4[j] = *(const float4*)&Bs[(8 * j + tx) * LDP + 4 * qd];
            #pragma unroll
            for (int i = 0; i < 8; ++i)
                #pragma unroll
                for (int j = 0; j < 8; ++j)
                    c[i][j] = fmaf(a4[i].x, b4[j].x,
                               fmaf(a4[i].y, b4[j].y,
                                fmaf(a4[i].z, b4[j].z,
                                 fmaf(a4[i].w, b4[j].w, c[i][j]))));
        }
        // next iteration's staging (same-wave) is ordered after these reads by program order
    }

    // epilogue: d2 = sq_i + sq_j - 2*G; 5-term gaussian kernel sums
    const bool iS = (i0 < HALF_N), jS = (j0 < HALF_N);
    const bool diagRegion = (iS == jS);
    const double wgt = (bi == bj) ? 1.0 : 2.0;
    const float L2E = 1.4426950408889634f;
    const float cxy = -L2E / bw[2];
    const float cdg = diagRegion ? (-L2E / (iS ? bw[0] : bw[1])) : 0.f;

    float sqi[8], sqj[8];
    #pragma unroll
    for (int a = 0; a < 8; ++a) {
        sqi[a] = sq[i0 + 8 * a + ty];
        sqj[a] = sq[j0 + 8 * a + tx];
    }

    float sxy = 0.f, sdg = 0.f;
    #pragma unroll
    for (int i = 0; i < 8; ++i) {
        #pragma unroll
        for (int j = 0; j < 8; ++j) {
            const float d2 = sqi[i] + sqj[j] - 2.f * c[i][j];
            {
                const float tt = d2 * cxy;
                sxy += exp2f(tt) + exp2f(tt * 0.5f) + exp2f(tt * 0.25f)
                     + exp2f(tt * 0.125f) + exp2f(tt * 0.0625f);
            }
            if (diagRegion) {
                const float tt = d2 * cdg;
                sdg += exp2f(tt) + exp2f(tt * 0.5f) + exp2f(tt * 0.25f)
                     + exp2f(tt * 0.125f) + exp2f(tt * 0.0625f);
            }
        }
    }

    #pragma unroll
    for (int off = 32; off; off >>= 1) {
        sxy += __shfl_xor(sxy, off);
        sdg += __shfl_xor(sdg, off);
    }
    if (tid == 0) {
        // partials[t] = {weighted xy-sum, weighted src-diag sum, weighted tgt-diag sum}
        partials[3 * t + 0] = wgt * (double)sxy;
        partials[3 * t + 1] = (diagRegion && iS) ? wgt * (double)sdg : 0.0;
        partials[3 * t + 2] = (diagRegion && !iS) ? wgt * (double)sdg : 0.0;
    }
}

// ---------------- Kernel 4: reduce partials + finalize ----------------
__global__ __launch_bounds__(256) void k_final(const double* __restrict__ partials,
                                               float* __restrict__ out) {
    const int tid = threadIdx.x;
    double pxy = 0, ps = 0, pt = 0;
    for (int i = tid; i < NWORK; i += 256) {
        pxy += partials[3 * i + 0];
        ps  += partials[3 * i + 1];
        pt  += partials[3 * i + 2];
    }
    #pragma unroll
    for (int off = 32; off; off >>= 1) {
        pxy += __shfl_xor(pxy, off);
        ps  += __shfl_xor(ps, off);
        pt  += __shfl_xor(pt, off);
    }
    __shared__ double red[4][3];
    const int w = tid >> 6, l = tid & 63;
    if (l == 0) { red[w][0] = pxy; red[w][1] = ps; red[w][2] = pt; }
    __syncthreads();
    if (tid == 0) {
        double xy = (red[0][0] + red[1][0] + red[2][0] + red[3][0])
                  / ((double)N_TOTAL * (double)N_TOTAL);
        double xx = (red[0][1] + red[1][1] + red[2][1] + red[3][1])
                  / ((double)HALF_N * (double)HALF_N);
        double yy = (red[0][2] + red[1][2] + red[2][2] + red[3][2])
                  / ((double)HALF_N * (double)HALF_N);
        out[0] = (float)(xx + yy - 2.0 * xy);
    }
}

extern "C" void kernel_launch(void* const* d_in, const int* in_sizes, int n_in,
                              void* d_out, int out_size, void* d_ws, size_t ws_size,
                              hipStream_t stream) {
    const float* latent = (const float*)d_in[0];
    // d_in[1] (domain) is unused: reference splits by position (fixed halves).

    char* wsb = (char*)d_ws;
    float*  sqv      = (float*)wsb;                 // 4096 floats
    float*  colsum   = (float*)(wsb + 16384);       // 1024 floats
    double* sumsq    = (double*)(wsb + 20480);      // 2 doubles
    float*  bw       = (float*)(wsb + 20520);       // 3 floats
    double* partials = (double*)(wsb + P_OFF);      // 2080*3 doubles (all written by k_main)

    // zero only the atomic-accumulated region (colsum + sumsq)
    (void)hipMemsetAsync(wsb + 16384, 0, 20496 - 16384, stream);

    k_rowstats<<<256, 256, 0, stream>>>(latent, sqv, colsum, sumsq);
    k_bw<<<1, 256, 0, stream>>>(colsum, sumsq, bw);
    k_main<<<NWORK, 64, 0, stream>>>(latent, sqv, bw, partials);
    k_final<<<1, 256, 0, stream>>>(partials, (float*)d_out);
}